// Round 3
// baseline (1217.127 us; speedup 1.0000x reference)
//
#include <hip/hip_runtime.h>
#include <hip/hip_bf16.h>

typedef unsigned short u16;

__device__ __forceinline__ float bf2f(u16 u){ return __uint_as_float(((unsigned)u) << 16); }
__device__ __forceinline__ u16 f2bf(float f){
    unsigned u = __float_as_uint(f);
    unsigned r = 0x7fffu + ((u >> 16) & 1u);
    return (u16)((u + r) >> 16);
}

// ---------------- problem constants ----------------
// Inputs (float32 unless noted):
//   noise (2,768,577) ; targets (2,384,384) int32 ; w1 (512,768,3,3) ; b1 (512)
//   w2 (512,512,3,3) ; b2 (512) ; w3 (77) ; b3 (77)
// Outputs (float32!  R1/R2 evidence: harness reads f32):
//   out0 = transpose(noise,(2,0,1)) : (577,2,768)    = 886272
//   out1 = w3[o]*y[b,cls,c] + b3[o] : (2,77,171,512) = 13483008
#define OUT0_N 886272
#define OUT1_N 13483008

// ---------------- out0: transpose (f32 -> f32) ----------------
__global__ void k_out0(const float* __restrict__ noise, float* __restrict__ out0){
    int idx = blockIdx.x * 256 + threadIdx.x;
    if (idx >= OUT0_N) return;
    int c = idx % 768; int t = idx / 768;
    int b = t % 2;     int s = t / 2;
    out0[idx] = noise[(b * 768 + c) * 577 + s];
}

// ---------------- A = w1 reordered to [c1*9+tap][c0], f32 -> bf16 ----------------
__global__ void k_prepA(const float* __restrict__ w1, u16* __restrict__ Are){
    int idx = blockIdx.x * 256 + threadIdx.x;    // 4608*768
    if (idx >= 4608 * 768) return;
    int k = idx % 768; int m = idx / 768;
    int c1 = m / 9, tap = m % 9;
    Are[idx] = f2bf(w1[(size_t)(c1 * 768 + k) * 9 + tap]);
}

// ---------------- labels m[b,i,j] = targets[b,16i,16j] ----------------
__global__ void k_labels(const int* __restrict__ targets, int* __restrict__ labels){
    int idx = blockIdx.x * blockDim.x + threadIdx.x;   // 1152
    if (idx >= 1152) return;
    int b = idx / 576; int p = idx % 576;
    int i = p / 24, j = p % 24;
    labels[idx] = targets[b * 147456 + i * 16 * 384 + j * 16];
}

// ---------------- bias_eff init: b2 ----------------
__global__ void k_biasinit(const float* __restrict__ b2, float* __restrict__ bias){
    int c2 = blockIdx.x * blockDim.x + threadIdx.x;
    if (c2 < 512) bias[c2] = b2[c2];
}

// ---------------- Mfull[c2][c1*9 + rho*3+tau] and bias_eff accumulation ----------------
// Mfull = (1/576) * sum_{a: rho in cats(a), b': tau in cats(b')} w2[c2,c1,a,b']
// cat rho=0 (u<4) hit by a in {0,1}; rho=1 (4<=u<20) by {0,1,2}; rho=2 (u>=20) by {1,2}.
// bias_eff[c2] += b1[c1] * (1/36) * sum_{a,b'} w2[c2,c1,a,b']*cnt[a]*cnt[b'], cnt={5,6,5}
__global__ void k_Mfull(const float* __restrict__ w2, const float* __restrict__ b1,
                        float* __restrict__ Mfull, float* __restrict__ bias){
    int idx = blockIdx.x * 256 + threadIdx.x;   // 512*512
    if (idx >= 512 * 512) return;
    int c1 = idx % 512, c2 = idx / 512;
    const float* wp = w2 + (size_t)(c2 * 512 + c1) * 9;
    float t[3][3];
    #pragma unroll
    for (int r = 0; r < 3; r++)
        #pragma unroll
        for (int s = 0; s < 3; s++)
            t[r][s] = wp[r * 3 + s];
    float cs0[3], cs1[3], cs2[3];
    #pragma unroll
    for (int r = 0; r < 3; r++){
        cs0[r] = t[r][0] + t[r][1];
        cs1[r] = t[r][0] + t[r][1] + t[r][2];
        cs2[r] = t[r][1] + t[r][2];
    }
    const float inv = 1.0f / 576.0f;
    float* Mp = Mfull + (size_t)(c2 * 512 + c1) * 9;
    Mp[0] = inv * (cs0[0] + cs0[1]);
    Mp[1] = inv * (cs1[0] + cs1[1]);
    Mp[2] = inv * (cs2[0] + cs2[1]);
    Mp[3] = inv * (cs0[0] + cs0[1] + cs0[2]);
    Mp[4] = inv * (cs1[0] + cs1[1] + cs1[2]);
    Mp[5] = inv * (cs2[0] + cs2[1] + cs2[2]);
    Mp[6] = inv * (cs0[1] + cs0[2]);
    Mp[7] = inv * (cs1[1] + cs1[2]);
    Mp[8] = inv * (cs2[1] + cs2[2]);
    const float cw[3] = {5.f, 6.f, 5.f};
    float sb = 0.f;
    #pragma unroll
    for (int r = 0; r < 3; r++)
        #pragma unroll
        for (int s = 0; s < 3; s++)
            sb += t[r][s] * cw[r] * cw[s];
    atomicAdd(&bias[c2], b1[c1] * sb * (1.0f / 36.0f));
}

// ---------------- GEMM1: D[m=4608][n=1152] = Are[m][k=768] * X[k][n] ----------------
// X[k][n] = noise[(b*768+k)*577 + 1 + pix], n = b*576 + pix. 576 % 64 == 0 so tiles
// never straddle the batch boundary.
__launch_bounds__(256)
__global__ void k_gemm1(const u16* __restrict__ Are, const float* __restrict__ noise,
                        float* __restrict__ D){
    __shared__ __align__(16) float As[16][68];
    __shared__ __align__(16) float Bs[16][68];
    int m0 = blockIdx.x * 64;
    int n0 = blockIdx.y * 64;
    int t  = threadIdx.x;
    int tx = t % 16, ty = t / 16;
    int b    = n0 / 576;
    int pix0 = n0 % 576;
    float acc[4][4] = {};
    for (int k0 = 0; k0 < 768; k0 += 16){
        #pragma unroll
        for (int e = t; e < 64 * 16; e += 256){
            int r = e / 16, c = e % 16;                     // r: m-local, c: k-local
            As[c][r] = bf2f(Are[(size_t)(m0 + r) * 768 + k0 + c]);
        }
        #pragma unroll
        for (int e = t; e < 16 * 64; e += 256){
            int r = e / 64, c = e % 64;                     // r: k-local, c: n-local
            Bs[r][c] = noise[(size_t)(b * 768 + k0 + r) * 577 + 1 + pix0 + c];
        }
        __syncthreads();
        #pragma unroll
        for (int kk = 0; kk < 16; kk++){
            float4 a4 = *(const float4*)&As[kk][ty * 4];
            float4 b4 = *(const float4*)&Bs[kk][tx * 4];
            float a[4] = {a4.x, a4.y, a4.z, a4.w};
            float bb[4] = {b4.x, b4.y, b4.z, b4.w};
            #pragma unroll
            for (int mi = 0; mi < 4; mi++)
                #pragma unroll
                for (int ni = 0; ni < 4; ni++)
                    acc[mi][ni] += a[mi] * bb[ni];
        }
        __syncthreads();
    }
    #pragma unroll
    for (int mi = 0; mi < 4; mi++){
        float4 v = make_float4(acc[mi][0], acc[mi][1], acc[mi][2], acc[mi][3]);
        *(float4*)&D[(size_t)(m0 + ty * 4 + mi) * 1152 + n0 + tx * 4] = v;
    }
}

// ---------------- scatter: D taps -> Zcat[b*171+cls][c1*9 + rho*3+tau] ----------------
__global__ void k_scatter(const float* __restrict__ D, const int* __restrict__ labels,
                          float* __restrict__ Zcat){
    int idx = blockIdx.x * 256 + threadIdx.x;  // 512*1152, n fastest for coalescing
    if (idx >= 512 * 1152) return;
    int n  = idx % 1152;
    int c1 = idx / 1152;
    int b = n / 576, p = n % 576;
    int i = p / 24, j = p % 24;
    int cls = labels[n];
    if (cls < 0 || cls >= 171) return;   // labels >=171 have all-zero mask in ref
    float slot[9];
    #pragma unroll
    for (int q = 0; q < 9; q++) slot[q] = 0.f;
    bool ur[3] = {false, false, false}, uc[3] = {false, false, false};
    int tau[3]; bool vs[3];
    #pragma unroll
    for (int s1 = 0; s1 < 3; s1++){
        int v = j - s1 + 1;
        vs[s1]  = (v >= 0 && v < 24);
        tau[s1] = (v < 4) ? 0 : ((v < 20) ? 1 : 2);
    }
    #pragma unroll
    for (int r1 = 0; r1 < 3; r1++){
        int u = i - r1 + 1;
        if (u < 0 || u >= 24) continue;
        int rho = (u < 4) ? 0 : ((u < 20) ? 1 : 2);
        ur[rho] = true;
        #pragma unroll
        for (int s1 = 0; s1 < 3; s1++){
            if (!vs[s1]) continue;
            float tv = D[(size_t)(c1 * 9 + r1 * 3 + s1) * 1152 + n];
            slot[rho * 3 + tau[s1]] += tv;
            uc[tau[s1]] = true;
        }
    }
    float* zp = Zcat + (size_t)(b * 171 + cls) * 4608 + c1 * 9;
    #pragma unroll
    for (int rho = 0; rho < 3; rho++)
        #pragma unroll
        for (int tq = 0; tq < 3; tq++)
            if (ur[rho] && uc[tq]) atomicAdd(&zp[rho * 3 + tq], slot[rho * 3 + tq]);
}

// ---------------- GEMM2: y[n2=342][c2=512] = sum_k Mfull[c2][k]*Zcat[n2][k] + bias[c2] ----------------
__launch_bounds__(256)
__global__ void k_gemm2(const float* __restrict__ Mfull, const float* __restrict__ Zcat,
                        const float* __restrict__ bias, float* __restrict__ y){
    __shared__ __align__(16) float As[16][68];
    __shared__ __align__(16) float Bs[16][68];
    int m0 = blockIdx.x * 64;   // c2
    int n0 = blockIdx.y * 64;   // n2
    int t  = threadIdx.x;
    int tx = t % 16, ty = t / 16;
    float acc[4][4] = {};
    for (int k0 = 0; k0 < 4608; k0 += 16){
        #pragma unroll
        for (int e = t; e < 1024; e += 256){
            int r = e / 16, c = e % 16;                    // r: m-local, c: k-local
            As[c][r] = Mfull[(size_t)(m0 + r) * 4608 + k0 + c];
        }
        #pragma unroll
        for (int e = t; e < 1024; e += 256){
            int r = e / 16, c = e % 16;                    // r: n-local, c: k-local
            int n = n0 + r;
            Bs[c][r] = (n < 342) ? Zcat[(size_t)n * 4608 + k0 + c] : 0.f;
        }
        __syncthreads();
        #pragma unroll
        for (int kk = 0; kk < 16; kk++){
            float4 a4 = *(const float4*)&As[kk][ty * 4];
            float4 b4 = *(const float4*)&Bs[kk][tx * 4];
            float a[4] = {a4.x, a4.y, a4.z, a4.w};
            float bb[4] = {b4.x, b4.y, b4.z, b4.w};
            #pragma unroll
            for (int mi = 0; mi < 4; mi++)
                #pragma unroll
                for (int ni = 0; ni < 4; ni++)
                    acc[mi][ni] += a[mi] * bb[ni];
        }
        __syncthreads();
    }
    #pragma unroll
    for (int ni = 0; ni < 4; ni++){
        int n = n0 + tx * 4 + ni;
        if (n >= 342) continue;
        float4 v;
        v.x = acc[0][ni] + bias[m0 + ty * 4 + 0];
        v.y = acc[1][ni] + bias[m0 + ty * 4 + 1];
        v.z = acc[2][ni] + bias[m0 + ty * 4 + 2];
        v.w = acc[3][ni] + bias[m0 + ty * 4 + 3];
        *(float4*)&y[(size_t)n * 512 + m0 + ty * 4] = v;
    }
}

// ---------------- final expansion: out1[b,o,cls,c] = w3[o]*y[b,cls,c] + b3[o] (f32) ----------------
__global__ void k_final(const float* __restrict__ y, const float* __restrict__ w3,
                        const float* __restrict__ b3, float* __restrict__ out1){
    int idx = blockIdx.x * 256 + threadIdx.x;   // 13483008
    if (idx >= OUT1_N) return;
    int c = idx & 511;
    int r = idx >> 9;          // (b*77 + o)*171 + cls
    int cls = r % 171; r /= 171;
    int o = r % 77;
    int b = r / 77;
    out1[idx] = w3[o] * y[(size_t)(b * 171 + cls) * 512 + c] + b3[o];
}

extern "C" void kernel_launch(void* const* d_in, const int* in_sizes, int n_in,
                              void* d_out, int out_size, void* d_ws, size_t ws_size,
                              hipStream_t stream) {
    const float* noise   = (const float*)d_in[0];
    const int*   targets = (const int*)  d_in[1];
    const float* w1      = (const float*)d_in[2];
    const float* b1      = (const float*)d_in[3];
    const float* w2      = (const float*)d_in[4];
    const float* b2      = (const float*)d_in[5];
    const float* w3      = (const float*)d_in[6];
    const float* b3      = (const float*)d_in[7];
    float* out0 = (float*)d_out;
    float* out1 = out0 + OUT0_N;

    char* ws = (char*)d_ws;
    const size_t OFF_ARE  = 0;                        // 4608*768*2  = 7,077,888
    const size_t OFF_D    = 7077888;                  // 4608*1152*4 = 21,233,664
    const size_t OFF_MF   = OFF_D   + 21233664;       // 512*4608*4  = 9,437,184
    const size_t OFF_ZC   = OFF_MF  + 9437184;        // 342*4608*4  = 6,303,744
    const size_t OFF_Y    = OFF_ZC  + 6303744;        // 342*512*4   = 700,416
    const size_t OFF_BIAS = OFF_Y   + 700416;         // 2048
    const size_t OFF_LAB  = OFF_BIAS + 2048;          // 4608

    u16*   Are   = (u16*)  (ws + OFF_ARE);
    float* D     = (float*)(ws + OFF_D);
    float* Mfull = (float*)(ws + OFF_MF);
    float* Zcat  = (float*)(ws + OFF_ZC);
    float* yb    = (float*)(ws + OFF_Y);
    float* bias  = (float*)(ws + OFF_BIAS);
    int*   labels= (int*)  (ws + OFF_LAB);

    hipMemsetAsync(Zcat, 0, (size_t)342 * 4608 * 4, stream);

    k_biasinit<<<2, 256, 0, stream>>>(b2, bias);
    k_labels<<<5, 256, 0, stream>>>(targets, labels);
    k_out0<<<OUT0_N / 256, 256, 0, stream>>>(noise, out0);
    k_prepA<<<(4608 * 768) / 256, 256, 0, stream>>>(w1, Are);
    k_Mfull<<<(512 * 512) / 256, 256, 0, stream>>>(w2, b1, Mfull, bias);
    k_gemm1<<<dim3(72, 18), 256, 0, stream>>>(Are, noise, D);
    k_scatter<<<(512 * 1152) / 256, 256, 0, stream>>>(D, labels, Zcat);
    k_gemm2<<<dim3(8, 6), 256, 0, stream>>>(Mfull, Zcat, bias, yb);
    k_final<<<OUT1_N / 256, 256, 0, stream>>>(yb, w3, b3, out1);
}

// Round 4
// 294.091 us; speedup vs baseline: 4.1386x; 4.1386x over previous
//
#include <hip/hip_runtime.h>
#include <hip/hip_bf16.h>

typedef unsigned short u16;
typedef short bf16x8 __attribute__((ext_vector_type(8)));
typedef float f32x4 __attribute__((ext_vector_type(4)));

__device__ __forceinline__ u16 f2bf(float f){
    unsigned u = __float_as_uint(f);
    unsigned r = 0x7fffu + ((u >> 16) & 1u);
    return (u16)((u + r) >> 16);
}

// ---------------- problem constants ----------------
// Inputs f32 (targets i32): noise(2,768,577) targets(2,384,384) w1(512,768,3,3)
// b1(512) w2(512,512,3,3) b2(512) w3(77) b3(77)
// Outputs f32: out0 transpose(noise) (577,2,768)=886272 ; out1 (2,77,171,512)=13483008
#define OUT0_N 886272
#define OUT1_N 13483008
#define YN 175104           // 342*512
#define KSPLIT 24           // gemm2 K-split: 4608/24 = 192

// ---------------- out0: transpose ----------------
__global__ void k_out0(const float* __restrict__ noise, float* __restrict__ out0){
    int idx = blockIdx.x * 256 + threadIdx.x;
    if (idx >= OUT0_N) return;
    int c = idx % 768; int t = idx / 768;
    int b = t % 2;     int s = t / 2;
    out0[idx] = noise[(b * 768 + c) * 577 + s];
}

// ---------------- Are[c1*9+tap][c0] bf16 ; thread per (c1,c0): 36B contiguous read ----------------
__global__ void k_prepA(const float* __restrict__ w1, u16* __restrict__ Are){
    int idx = blockIdx.x * 256 + threadIdx.x;    // 512*768
    if (idx >= 512 * 768) return;
    int k = idx % 768; int c1 = idx / 768;
    const float* wp = w1 + (size_t)idx * 9;
    #pragma unroll
    for (int tap = 0; tap < 9; tap++)
        Are[(size_t)(c1 * 9 + tap) * 768 + k] = f2bf(wp[tap]);
}

// ---------------- XbfT[n][k] = bf16(noise[b,k,1+pix]), n=b*576+pix ----------------
__global__ void k_prepX(const float* __restrict__ noise, u16* __restrict__ XbfT){
    int idx = blockIdx.x * 256 + threadIdx.x;    // 1152*768, k fastest (coalesced write)
    if (idx >= 1152 * 768) return;
    int k = idx % 768; int n = idx / 768;
    int b = n / 576, pix = n % 576;
    XbfT[idx] = f2bf(noise[(size_t)(b * 768 + k) * 577 + 1 + pix]);
}

// ---------------- labels ----------------
__global__ void k_labels(const int* __restrict__ targets, int* __restrict__ labels){
    int idx = blockIdx.x * blockDim.x + threadIdx.x;   // 1152
    if (idx >= 1152) return;
    int b = idx / 576; int p = idx % 576;
    int i = p / 24, j = p % 24;
    labels[idx] = targets[b * 147456 + i * 16 * 384 + j * 16];
}

// ---------------- bias_eff[c2] = b2[c2] + (1/36)*sum_c1 b1[c1]*sum_taps w2*cnt ----------------
__global__ void k_bias(const float* __restrict__ w2, const float* __restrict__ b1,
                       const float* __restrict__ b2, float* __restrict__ bias){
    int c2 = blockIdx.x; int t = threadIdx.x;
    const float cw[9] = {25.f,30.f,25.f,30.f,36.f,30.f,25.f,30.f,25.f};
    float sb = 0.f;
    for (int c1 = t; c1 < 512; c1 += 256){
        const float* wp = w2 + (size_t)(c2 * 512 + c1) * 9;
        float s = 0.f;
        #pragma unroll
        for (int q = 0; q < 9; q++) s += wp[q] * cw[q];
        sb += b1[c1] * s;
    }
    __shared__ float red[256];
    red[t] = sb; __syncthreads();
    for (int o = 128; o > 0; o >>= 1){ if (t < o) red[t] += red[t + o]; __syncthreads(); }
    if (t == 0) bias[c2] = b2[c2] + red[0] * (1.0f / 36.0f);
}

// ---------------- Mfull[c2][c1*9 + rho*3+tau] ----------------
__global__ void k_Mfull(const float* __restrict__ w2, float* __restrict__ Mfull){
    int idx = blockIdx.x * 256 + threadIdx.x;   // 512*512
    if (idx >= 512 * 512) return;
    int c1 = idx % 512, c2 = idx / 512;
    const float* wp = w2 + (size_t)(c2 * 512 + c1) * 9;
    float t[3][3];
    #pragma unroll
    for (int r = 0; r < 3; r++)
        #pragma unroll
        for (int s = 0; s < 3; s++)
            t[r][s] = wp[r * 3 + s];
    float cs0[3], cs1[3], cs2[3];
    #pragma unroll
    for (int r = 0; r < 3; r++){
        cs0[r] = t[r][0] + t[r][1];
        cs1[r] = t[r][0] + t[r][1] + t[r][2];
        cs2[r] = t[r][1] + t[r][2];
    }
    const float inv = 1.0f / 576.0f;
    float* Mp = Mfull + (size_t)(c2 * 512 + c1) * 9;
    Mp[0] = inv * (cs0[0] + cs0[1]);
    Mp[1] = inv * (cs1[0] + cs1[1]);
    Mp[2] = inv * (cs2[0] + cs2[1]);
    Mp[3] = inv * (cs0[0] + cs0[1] + cs0[2]);
    Mp[4] = inv * (cs1[0] + cs1[1] + cs1[2]);
    Mp[5] = inv * (cs2[0] + cs2[1] + cs2[2]);
    Mp[6] = inv * (cs0[1] + cs0[2]);
    Mp[7] = inv * (cs1[1] + cs1[2]);
    Mp[8] = inv * (cs2[1] + cs2[2]);
}

// ---------------- GEMM1 (MFMA bf16): D[4608][1152] = Are[m][k=768] * XbfT[n][k]^T ----------------
// Block 128m x 64n, 4 waves 2x2, wave tile 64m x 32n. Fragments load directly from
// global (both operands are [row][k] with k contiguous -> 16B/lane).
__launch_bounds__(256)
__global__ void k_gemm1(const u16* __restrict__ Are, const u16* __restrict__ XbfT,
                        float* __restrict__ D){
    int wave = threadIdx.x >> 6;
    int lane = threadIdx.x & 63;
    int l16 = lane & 15, quad = lane >> 4;
    int wm = wave >> 1, wn = wave & 1;
    int m0 = blockIdx.x * 128 + wm * 64;
    int n0 = blockIdx.y * 64  + wn * 32;
    const u16* Ap = Are  + (size_t)(m0 + l16) * 768 + quad * 8;
    const u16* Bp = XbfT + (size_t)(n0 + l16) * 768 + quad * 8;
    f32x4 acc[4][2] = {};
    for (int k0 = 0; k0 < 768; k0 += 32){
        bf16x8 a[4], b[2];
        #pragma unroll
        for (int i = 0; i < 4; i++) a[i] = *(const bf16x8*)(Ap + (size_t)i * 16 * 768 + k0);
        #pragma unroll
        for (int i = 0; i < 2; i++) b[i] = *(const bf16x8*)(Bp + (size_t)i * 16 * 768 + k0);
        #pragma unroll
        for (int mi = 0; mi < 4; mi++)
            #pragma unroll
            for (int ni = 0; ni < 2; ni++)
                acc[mi][ni] = __builtin_amdgcn_mfma_f32_16x16x32_bf16(a[mi], b[ni], acc[mi][ni], 0, 0, 0);
    }
    // C/D layout: col = lane&15, row = quad*4 + reg   [m89/m91-verified]
    #pragma unroll
    for (int mi = 0; mi < 4; mi++)
        #pragma unroll
        for (int ni = 0; ni < 2; ni++)
            #pragma unroll
            for (int r = 0; r < 4; r++)
                D[(size_t)(m0 + mi * 16 + quad * 4 + r) * 1152 + n0 + ni * 16 + l16] = acc[mi][ni][r];
}

// ---------------- scatter: D taps -> Zcat[b*171+cls][c1*9 + rho*3+tau] ----------------
__global__ void k_scatter(const float* __restrict__ D, const int* __restrict__ labels,
                          float* __restrict__ Zcat){
    int idx = blockIdx.x * 256 + threadIdx.x;  // 512*1152
    if (idx >= 512 * 1152) return;
    int n  = idx % 1152;
    int c1 = idx / 1152;
    int b = n / 576, p = n % 576;
    int i = p / 24, j = p % 24;
    int cls = labels[n];
    if (cls < 0 || cls >= 171) return;
    float slot[9];
    #pragma unroll
    for (int q = 0; q < 9; q++) slot[q] = 0.f;
    bool ur[3] = {false, false, false}, uc[3] = {false, false, false};
    int tau[3]; bool vs[3];
    #pragma unroll
    for (int s1 = 0; s1 < 3; s1++){
        int v = j - s1 + 1;
        vs[s1]  = (v >= 0 && v < 24);
        tau[s1] = (v < 4) ? 0 : ((v < 20) ? 1 : 2);
    }
    #pragma unroll
    for (int r1 = 0; r1 < 3; r1++){
        int u = i - r1 + 1;
        if (u < 0 || u >= 24) continue;
        int rho = (u < 4) ? 0 : ((u < 20) ? 1 : 2);
        ur[rho] = true;
        #pragma unroll
        for (int s1 = 0; s1 < 3; s1++){
            if (!vs[s1]) continue;
            float tv = D[(size_t)(c1 * 9 + r1 * 3 + s1) * 1152 + n];
            slot[rho * 3 + tau[s1]] += tv;
            uc[tau[s1]] = true;
        }
    }
    float* zp = Zcat + (size_t)(b * 171 + cls) * 4608 + c1 * 9;
    #pragma unroll
    for (int rho = 0; rho < 3; rho++)
        #pragma unroll
        for (int tq = 0; tq < 3; tq++)
            if (ur[rho] && uc[tq]) atomicAdd(&zp[rho * 3 + tq], slot[rho * 3 + tq]);
}

// ---------------- GEMM2 phase A: ypart[s][n][c2] partial over K-chunk 192 ----------------
__launch_bounds__(256)
__global__ void k_gemm2p(const float* __restrict__ Mfull, const float* __restrict__ Zcat,
                         float* __restrict__ ypart){
    __shared__ __align__(16) float As[16][68];
    __shared__ __align__(16) float Bs[16][68];
    int m0 = blockIdx.x * 64;   // c2
    int n0 = blockIdx.y * 64;   // n2
    int s  = blockIdx.z;
    int kbeg = s * 192;
    int t  = threadIdx.x;
    int tx = t % 16, ty = t / 16;
    float acc[4][4] = {};
    for (int k0 = kbeg; k0 < kbeg + 192; k0 += 16){
        #pragma unroll
        for (int e = t; e < 1024; e += 256){
            int r = e / 16, c = e % 16;
            As[c][r] = Mfull[(size_t)(m0 + r) * 4608 + k0 + c];
        }
        #pragma unroll
        for (int e = t; e < 1024; e += 256){
            int r = e / 16, c = e % 16;
            int n = n0 + r;
            Bs[c][r] = (n < 342) ? Zcat[(size_t)n * 4608 + k0 + c] : 0.f;
        }
        __syncthreads();
        #pragma unroll
        for (int kk = 0; kk < 16; kk++){
            float4 a4 = *(const float4*)&As[kk][ty * 4];
            float4 b4 = *(const float4*)&Bs[kk][tx * 4];
            float a[4] = {a4.x, a4.y, a4.z, a4.w};
            float bb[4] = {b4.x, b4.y, b4.z, b4.w};
            #pragma unroll
            for (int mi = 0; mi < 4; mi++)
                #pragma unroll
                for (int ni = 0; ni < 4; ni++)
                    acc[mi][ni] += a[mi] * bb[ni];
        }
        __syncthreads();
    }
    float* yp = ypart + (size_t)s * YN;
    #pragma unroll
    for (int ni = 0; ni < 4; ni++){
        int n = n0 + tx * 4 + ni;
        if (n >= 342) continue;
        float4 v = make_float4(acc[0][ni], acc[1][ni], acc[2][ni], acc[3][ni]);
        *(float4*)&yp[(size_t)n * 512 + m0 + ty * 4] = v;
    }
}

// ---------------- GEMM2 reduce: y = sum_s ypart + bias ----------------
__global__ void k_gemm2r(const float* __restrict__ ypart, const float* __restrict__ bias,
                         float* __restrict__ y){
    int idx = blockIdx.x * 256 + threadIdx.x;   // 175104
    if (idx >= YN) return;
    float sum = bias[idx & 511];
    #pragma unroll 4
    for (int s = 0; s < KSPLIT; s++) sum += ypart[(size_t)s * YN + idx];
    y[idx] = sum;
}

// ---------------- final: out1[b,o,cls,c] = w3[o]*y[b*171+cls][c] + b3[o], float4 ----------------
__global__ void k_final(const float* __restrict__ y, const float* __restrict__ w3,
                        const float* __restrict__ b3, float4* __restrict__ out1){
    int idx = blockIdx.x * 256 + threadIdx.x;   // OUT1_N/4 = 3370752
    if (idx >= OUT1_N / 4) return;
    int c4 = idx & 127;
    int r = idx >> 7;
    int cls = r % 171; r /= 171;
    int o = r % 77;
    int b = r / 77;
    float4 v = *(const float4*)&y[(size_t)(b * 171 + cls) * 512 + c4 * 4];
    float w = w3[o], bb = b3[o];
    out1[idx] = make_float4(w * v.x + bb, w * v.y + bb, w * v.z + bb, w * v.w + bb);
}

extern "C" void kernel_launch(void* const* d_in, const int* in_sizes, int n_in,
                              void* d_out, int out_size, void* d_ws, size_t ws_size,
                              hipStream_t stream) {
    const float* noise   = (const float*)d_in[0];
    const int*   targets = (const int*)  d_in[1];
    const float* w1      = (const float*)d_in[2];
    const float* b1      = (const float*)d_in[3];
    const float* w2      = (const float*)d_in[4];
    const float* b2      = (const float*)d_in[5];
    const float* w3      = (const float*)d_in[6];
    const float* b3      = (const float*)d_in[7];
    float* out0 = (float*)d_out;
    float* out1 = out0 + OUT0_N;

    char* ws = (char*)d_ws;
    const size_t OFF_ARE  = 0;                        // 4608*768*2  = 7,077,888
    const size_t OFF_X    = 7077888;                  // 1152*768*2  = 1,769,472
    const size_t OFF_D    = OFF_X   + 1769472;        // 4608*1152*4 = 21,233,664 (reused as ypart: 24*175104*4 = 16,809,984)
    const size_t OFF_MF   = OFF_D   + 21233664;       // 512*4608*4  = 9,437,184
    const size_t OFF_ZC   = OFF_MF  + 9437184;        // 342*4608*4  = 6,303,744
    const size_t OFF_Y    = OFF_ZC  + 6303744;        // 175104*4    = 700,416
    const size_t OFF_BIAS = OFF_Y   + 700416;         // 2048
    const size_t OFF_LAB  = OFF_BIAS + 2048;          // 4608

    u16*   Are   = (u16*)  (ws + OFF_ARE);
    u16*   XbfT  = (u16*)  (ws + OFF_X);
    float* D     = (float*)(ws + OFF_D);
    float* ypart = (float*)(ws + OFF_D);              // alias: D dead after k_scatter
    float* Mfull = (float*)(ws + OFF_MF);
    float* Zcat  = (float*)(ws + OFF_ZC);
    float* yb    = (float*)(ws + OFF_Y);
    float* bias  = (float*)(ws + OFF_BIAS);
    int*   labels= (int*)  (ws + OFF_LAB);

    hipMemsetAsync(Zcat, 0, (size_t)342 * 4608 * 4, stream);

    k_bias  <<<512, 256, 0, stream>>>(w2, b1, b2, bias);
    k_labels<<<5, 256, 0, stream>>>(targets, labels);
    k_out0  <<<(OUT0_N + 255) / 256, 256, 0, stream>>>(noise, out0);
    k_prepA <<<(512 * 768) / 256, 256, 0, stream>>>(w1, Are);
    k_prepX <<<(1152 * 768) / 256, 256, 0, stream>>>(noise, XbfT);
    k_Mfull <<<(512 * 512) / 256, 256, 0, stream>>>(w2, Mfull);
    k_gemm1 <<<dim3(36, 18), 256, 0, stream>>>(Are, XbfT, D);
    k_scatter<<<(512 * 1152) / 256, 256, 0, stream>>>(D, labels, Zcat);
    k_gemm2p<<<dim3(8, 6, KSPLIT), 256, 0, stream>>>(Mfull, Zcat, ypart);
    k_gemm2r<<<(YN + 255) / 256, 256, 0, stream>>>(ypart, bias, yb);
    k_final <<<(OUT1_N / 4 + 255) / 256, 256, 0, stream>>>(yb, w3, b3, (float4*)out1);
}

// Round 5
// 228.872 us; speedup vs baseline: 5.3179x; 1.2850x over previous
//
#include <hip/hip_runtime.h>
#include <hip/hip_bf16.h>

typedef unsigned short u16;
typedef short bf16x8 __attribute__((ext_vector_type(8)));
typedef float f32x4 __attribute__((ext_vector_type(4)));

__device__ __forceinline__ u16 f2bf(float f){
    unsigned u = __float_as_uint(f);
    unsigned r = 0x7fffu + ((u >> 16) & 1u);
    return (u16)((u + r) >> 16);
}

// ---------------- problem constants ----------------
// Inputs f32 (targets i32): noise(2,768,577) targets(2,384,384) w1(512,768,3,3)
// b1(512) w2(512,512,3,3) b2(512) w3(77) b3(77)
// Outputs f32: out0 transpose(noise) (577,2,768)=886272 ; out1 (2,77,171,512)=13483008
#define OUT0_N 886272
#define OUT1_N 13483008
#define YN 175104           // 342*512
#define KSPLIT 24           // gemm2 K-split: 4608/24 = 192

// ---------------- fused transpose: out0 (f32) + XbfT (bf16), LDS-tiled ----------------
// Reads noise[b][c][s] coalesced in s; writes out0[(s*2+b)*768+c] and
// XbfT[(b*576+s-1)*768+c] coalesced in c.
__global__ void k_trans(const float* __restrict__ noise, float* __restrict__ out0,
                        u16* __restrict__ XbfT){
    __shared__ float tile[32][33];
    int s0 = blockIdx.x * 32;
    int c0 = blockIdx.y * 32;
    int b  = blockIdx.z;
    int tx = threadIdx.x, ty = threadIdx.y;   // (32, 8)
    #pragma unroll
    for (int i = 0; i < 4; i++){
        int c = c0 + ty + i * 8;
        int s = s0 + tx;
        if (s < 577) tile[ty + i * 8][tx] = noise[(size_t)(b * 768 + c) * 577 + s];
    }
    __syncthreads();
    #pragma unroll
    for (int i = 0; i < 4; i++){
        int s = s0 + ty + i * 8;
        int c = c0 + tx;
        if (s >= 577) continue;
        float v = tile[tx][ty + i * 8];
        out0[(size_t)(s * 2 + b) * 768 + c] = v;
        if (s >= 1) XbfT[(size_t)(b * 576 + s - 1) * 768 + c] = f2bf(v);
    }
}

// ---------------- Are[c1*9+tap][c0] bf16 ; thread per (c1,c0): 36B contiguous read ----------------
__global__ void k_prepA(const float* __restrict__ w1, u16* __restrict__ Are){
    int idx = blockIdx.x * 256 + threadIdx.x;    // 512*768
    if (idx >= 512 * 768) return;
    int k = idx % 768; int c1 = idx / 768;
    const float* wp = w1 + (size_t)idx * 9;
    #pragma unroll
    for (int tap = 0; tap < 9; tap++)
        Are[(size_t)(c1 * 9 + tap) * 768 + k] = f2bf(wp[tap]);
}

// ---------------- labels ----------------
__global__ void k_labels(const int* __restrict__ targets, int* __restrict__ labels){
    int idx = blockIdx.x * blockDim.x + threadIdx.x;   // 1152
    if (idx >= 1152) return;
    int b = idx / 576; int p = idx % 576;
    int i = p / 24, j = p % 24;
    labels[idx] = targets[b * 147456 + i * 16 * 384 + j * 16];
}

// ---------------- bias_eff[c2] = b2[c2] + (1/36)*sum_c1 b1[c1]*sum_taps w2*cnt ----------------
__global__ void k_bias(const float* __restrict__ w2, const float* __restrict__ b1,
                       const float* __restrict__ b2, float* __restrict__ bias){
    int c2 = blockIdx.x; int t = threadIdx.x;
    const float cw[9] = {25.f,30.f,25.f,30.f,36.f,30.f,25.f,30.f,25.f};
    float sb = 0.f;
    for (int c1 = t; c1 < 512; c1 += 256){
        const float* wp = w2 + (size_t)(c2 * 512 + c1) * 9;
        float s = 0.f;
        #pragma unroll
        for (int q = 0; q < 9; q++) s += wp[q] * cw[q];
        sb += b1[c1] * s;
    }
    __shared__ float red[256];
    red[t] = sb; __syncthreads();
    for (int o = 128; o > 0; o >>= 1){ if (t < o) red[t] += red[t + o]; __syncthreads(); }
    if (t == 0) bias[c2] = b2[c2] + red[0] * (1.0f / 36.0f);
}

// ---------------- Mfull[c2][c1*9 + rho*3+tau] ----------------
__global__ void k_Mfull(const float* __restrict__ w2, float* __restrict__ Mfull){
    int idx = blockIdx.x * 256 + threadIdx.x;   // 512*512
    if (idx >= 512 * 512) return;
    int c1 = idx % 512, c2 = idx / 512;
    const float* wp = w2 + (size_t)(c2 * 512 + c1) * 9;
    float t[3][3];
    #pragma unroll
    for (int r = 0; r < 3; r++)
        #pragma unroll
        for (int s = 0; s < 3; s++)
            t[r][s] = wp[r * 3 + s];
    float cs0[3], cs1[3], cs2[3];
    #pragma unroll
    for (int r = 0; r < 3; r++){
        cs0[r] = t[r][0] + t[r][1];
        cs1[r] = t[r][0] + t[r][1] + t[r][2];
        cs2[r] = t[r][1] + t[r][2];
    }
    const float inv = 1.0f / 576.0f;
    float* Mp = Mfull + (size_t)(c2 * 512 + c1) * 9;
    Mp[0] = inv * (cs0[0] + cs0[1]);
    Mp[1] = inv * (cs1[0] + cs1[1]);
    Mp[2] = inv * (cs2[0] + cs2[1]);
    Mp[3] = inv * (cs0[0] + cs0[1] + cs0[2]);
    Mp[4] = inv * (cs1[0] + cs1[1] + cs1[2]);
    Mp[5] = inv * (cs2[0] + cs2[1] + cs2[2]);
    Mp[6] = inv * (cs0[1] + cs0[2]);
    Mp[7] = inv * (cs1[1] + cs1[2]);
    Mp[8] = inv * (cs2[1] + cs2[2]);
}

// ---------------- GEMM1 (MFMA bf16): D[4608][1152] = Are[m][k=768] * XbfT[n][k]^T ----------------
__launch_bounds__(256)
__global__ void k_gemm1(const u16* __restrict__ Are, const u16* __restrict__ XbfT,
                        float* __restrict__ D){
    int wave = threadIdx.x >> 6;
    int lane = threadIdx.x & 63;
    int l16 = lane & 15, quad = lane >> 4;
    int wm = wave >> 1, wn = wave & 1;
    int m0 = blockIdx.x * 128 + wm * 64;
    int n0 = blockIdx.y * 64  + wn * 32;
    const u16* Ap = Are  + (size_t)(m0 + l16) * 768 + quad * 8;
    const u16* Bp = XbfT + (size_t)(n0 + l16) * 768 + quad * 8;
    f32x4 acc[4][2] = {};
    for (int k0 = 0; k0 < 768; k0 += 32){
        bf16x8 a[4], b[2];
        #pragma unroll
        for (int i = 0; i < 4; i++) a[i] = *(const bf16x8*)(Ap + (size_t)i * 16 * 768 + k0);
        #pragma unroll
        for (int i = 0; i < 2; i++) b[i] = *(const bf16x8*)(Bp + (size_t)i * 16 * 768 + k0);
        #pragma unroll
        for (int mi = 0; mi < 4; mi++)
            #pragma unroll
            for (int ni = 0; ni < 2; ni++)
                acc[mi][ni] = __builtin_amdgcn_mfma_f32_16x16x32_bf16(a[mi], b[ni], acc[mi][ni], 0, 0, 0);
    }
    #pragma unroll
    for (int mi = 0; mi < 4; mi++)
        #pragma unroll
        for (int ni = 0; ni < 2; ni++)
            #pragma unroll
            for (int r = 0; r < 4; r++)
                D[(size_t)(m0 + mi * 16 + quad * 4 + r) * 1152 + n0 + ni * 16 + l16] = acc[mi][ni][r];
}

// ---------------- scatter v2: one block per (b,c1); LDS class-histogram; plain stores ----------------
__launch_bounds__(256)
__global__ void k_scatter(const float* __restrict__ D, const int* __restrict__ labels,
                          float* __restrict__ Zcat){
    int blk = blockIdx.x;            // 0..1023
    int b  = blk >> 9;
    int c1 = blk & 511;
    __shared__ float acc[171 * 9];
    int t = threadIdx.x;
    for (int q = t; q < 1539; q += 256) acc[q] = 0.f;
    __syncthreads();
    for (int p = t; p < 576; p += 256){
        int cls = labels[b * 576 + p];
        if (cls < 0 || cls >= 171) continue;
        int i = p / 24, j = p % 24;
        float slot[9];
        #pragma unroll
        for (int q = 0; q < 9; q++) slot[q] = 0.f;
        unsigned used = 0;
        int tau[3]; bool vs[3];
        #pragma unroll
        for (int s1 = 0; s1 < 3; s1++){
            int v = j - s1 + 1;
            vs[s1]  = (v >= 0 && v < 24);
            tau[s1] = (v < 4) ? 0 : ((v < 20) ? 1 : 2);
        }
        #pragma unroll
        for (int r1 = 0; r1 < 3; r1++){
            int u = i - r1 + 1;
            if (u < 0 || u >= 24) continue;
            int rho = (u < 4) ? 0 : ((u < 20) ? 1 : 2);
            #pragma unroll
            for (int s1 = 0; s1 < 3; s1++){
                if (!vs[s1]) continue;
                float tv = D[(size_t)(c1 * 9 + r1 * 3 + s1) * 1152 + b * 576 + p];
                int sl = rho * 3 + tau[s1];
                slot[sl] += tv;
                used |= 1u << sl;
            }
        }
        #pragma unroll
        for (int sl = 0; sl < 9; sl++)
            if (used & (1u << sl)) atomicAdd(&acc[cls * 9 + sl], slot[sl]);
    }
    __syncthreads();
    for (int q = t; q < 1539; q += 256){
        int cls = q / 9, sl = q % 9;
        Zcat[(size_t)(b * 171 + cls) * 4608 + c1 * 9 + sl] = acc[q];
    }
}

// ---------------- GEMM2 phase A: ypart[s][n][c2] partial over K-chunk 192 ----------------
__launch_bounds__(256)
__global__ void k_gemm2p(const float* __restrict__ Mfull, const float* __restrict__ Zcat,
                         float* __restrict__ ypart){
    __shared__ __align__(16) float As[16][68];
    __shared__ __align__(16) float Bs[16][68];
    int m0 = blockIdx.x * 64;   // c2
    int n0 = blockIdx.y * 64;   // n2
    int s  = blockIdx.z;
    int kbeg = s * 192;
    int t  = threadIdx.x;
    int tx = t % 16, ty = t / 16;
    float acc[4][4] = {};
    for (int k0 = kbeg; k0 < kbeg + 192; k0 += 16){
        #pragma unroll
        for (int e = t; e < 1024; e += 256){
            int r = e / 16, c = e % 16;
            As[c][r] = Mfull[(size_t)(m0 + r) * 4608 + k0 + c];
        }
        #pragma unroll
        for (int e = t; e < 1024; e += 256){
            int r = e / 16, c = e % 16;
            int n = n0 + r;
            Bs[c][r] = (n < 342) ? Zcat[(size_t)n * 4608 + k0 + c] : 0.f;
        }
        __syncthreads();
        #pragma unroll
        for (int kk = 0; kk < 16; kk++){
            float4 a4 = *(const float4*)&As[kk][ty * 4];
            float4 b4 = *(const float4*)&Bs[kk][tx * 4];
            float a[4] = {a4.x, a4.y, a4.z, a4.w};
            float bb[4] = {b4.x, b4.y, b4.z, b4.w};
            #pragma unroll
            for (int mi = 0; mi < 4; mi++)
                #pragma unroll
                for (int ni = 0; ni < 4; ni++)
                    acc[mi][ni] += a[mi] * bb[ni];
        }
        __syncthreads();
    }
    float* yp = ypart + (size_t)s * YN;
    #pragma unroll
    for (int ni = 0; ni < 4; ni++){
        int n = n0 + tx * 4 + ni;
        if (n >= 342) continue;
        float4 v = make_float4(acc[0][ni], acc[1][ni], acc[2][ni], acc[3][ni]);
        *(float4*)&yp[(size_t)n * 512 + m0 + ty * 4] = v;
    }
}

// ---------------- GEMM2 reduce: y = sum_s ypart + bias ----------------
__global__ void k_gemm2r(const float* __restrict__ ypart, const float* __restrict__ bias,
                         float* __restrict__ y){
    int idx = blockIdx.x * 256 + threadIdx.x;   // 175104
    if (idx >= YN) return;
    float sum = bias[idx & 511];
    #pragma unroll 4
    for (int s = 0; s < KSPLIT; s++) sum += ypart[(size_t)s * YN + idx];
    y[idx] = sum;
}

// ---------------- final: out1[b,o,cls,c] = w3[o]*y[b*171+cls][c] + b3[o], float4 ----------------
__global__ void k_final(const float* __restrict__ y, const float* __restrict__ w3,
                        const float* __restrict__ b3, float4* __restrict__ out1){
    int idx = blockIdx.x * 256 + threadIdx.x;   // OUT1_N/4 = 3370752
    if (idx >= OUT1_N / 4) return;
    int c4 = idx & 127;
    int r = idx >> 7;
    int cls = r % 171; r /= 171;
    int o = r % 77;
    int b = r / 77;
    float4 v = *(const float4*)&y[(size_t)(b * 171 + cls) * 512 + c4 * 4];
    float w = w3[o], bb = b3[o];
    out1[idx] = make_float4(w * v.x + bb, w * v.y + bb, w * v.z + bb, w * v.w + bb);
}

extern "C" void kernel_launch(void* const* d_in, const int* in_sizes, int n_in,
                              void* d_out, int out_size, void* d_ws, size_t ws_size,
                              hipStream_t stream) {
    const float* noise   = (const float*)d_in[0];
    const int*   targets = (const int*)  d_in[1];
    const float* w1      = (const float*)d_in[2];
    const float* b1      = (const float*)d_in[3];
    const float* w2      = (const float*)d_in[4];
    const float* b2      = (const float*)d_in[5];
    const float* w3      = (const float*)d_in[6];
    const float* b3      = (const float*)d_in[7];
    float* out0 = (float*)d_out;
    float* out1 = out0 + OUT0_N;

    char* ws = (char*)d_ws;
    const size_t OFF_ARE  = 0;                        // 4608*768*2  = 7,077,888
    const size_t OFF_X    = 7077888;                  // 1152*768*2  = 1,769,472
    const size_t OFF_D    = OFF_X   + 1769472;        // 21,233,664 (reused as ypart)
    const size_t OFF_MF   = OFF_D   + 21233664;       // 9,437,184
    const size_t OFF_ZC   = OFF_MF  + 9437184;        // 6,303,744
    const size_t OFF_Y    = OFF_ZC  + 6303744;        // 700,416
    const size_t OFF_BIAS = OFF_Y   + 700416;         // 2048
    const size_t OFF_LAB  = OFF_BIAS + 2048;          // 4608

    u16*   Are   = (u16*)  (ws + OFF_ARE);
    u16*   XbfT  = (u16*)  (ws + OFF_X);
    float* D     = (float*)(ws + OFF_D);
    float* ypart = (float*)(ws + OFF_D);              // alias: D dead after k_scatter
    float* Mfull = (float*)(ws + OFF_MF);
    float* Zcat  = (float*)(ws + OFF_ZC);
    float* yb    = (float*)(ws + OFF_Y);
    float* bias  = (float*)(ws + OFF_BIAS);
    int*   labels= (int*)  (ws + OFF_LAB);

    k_bias  <<<512, 256, 0, stream>>>(w2, b1, b2, bias);
    k_labels<<<5, 256, 0, stream>>>(targets, labels);
    k_trans <<<dim3(19, 24, 2), dim3(32, 8), 0, stream>>>(noise, out0, XbfT);
    k_prepA <<<(512 * 768) / 256, 256, 0, stream>>>(w1, Are);
    k_Mfull <<<(512 * 512) / 256, 256, 0, stream>>>(w2, Mfull);
    k_gemm1 <<<dim3(36, 18), 256, 0, stream>>>(Are, XbfT, D);
    k_scatter<<<1024, 256, 0, stream>>>(D, labels, Zcat);
    k_gemm2p<<<dim3(8, 6, KSPLIT), 256, 0, stream>>>(Mfull, Zcat, ypart);
    k_gemm2r<<<(YN + 255) / 256, 256, 0, stream>>>(ypart, bias, yb);
    k_final <<<(OUT1_N / 4 + 255) / 256, 256, 0, stream>>>(yb, w3, b3, (float4*)out1);
}